// Round 14
// baseline (1163.146 us; speedup 1.0000x reference)
//
#include <hip/hip_runtime.h>
#include <hip/hip_fp16.h>

#define BB 16
#define TT 4096
#define TSZ 64
#define DE 128
#define HH 256
#define LDIM 512
#define ODIM 10
#define NBLKS 6
#define EPSF 1e-5f
#define NC32 128          // 32-token chunks
#define NROWS (BB*TT)     // 65536

typedef _Float16 f16x8 __attribute__((ext_vector_type(8)));
typedef float f32x4 __attribute__((ext_vector_type(4)));
#define MFMA16(a,b,c) __builtin_amdgcn_mfma_f32_16x16x32_f16((a),(b),(c),0,0,0)

// ---- f16 weight region layout ----
enum : size_t {
  HOFF_BG = 0,                                  // [NBLK][512][128]
  HOFF_WC = HOFF_BG + (size_t)NBLKS*512*128,    // [NBLK][128][512]  [d][h]=Cre, [d][256+h]=-Cim
  HOFF_W1 = HOFF_WC + (size_t)NBLKS*128*512,    // [NBLK][512][128]
  HOFF_W2 = HOFF_W1 + (size_t)NBLKS*512*128,    // [NBLK][128][256]
  HOFF_WE = HOFF_W2 + (size_t)NBLKS*128*256,    // [128][64]
  HOFF_PA = HOFF_WE + 128*64,                   // [NBLK][32][512]  A-plane (f16)
  HOFF_PB = HOFF_PA + (size_t)NBLKS*32*512,     // [NBLK][32][512]  B-plane (f16)
  HTOT_HALFS = HOFF_PB + (size_t)NBLKS*32*512
};

// ---- workspace layout (float offsets) ----
enum : size_t {
  WOFF_Y     = 0,
  WOFF_H     = WOFF_Y + (size_t)NROWS*DE/2,
  WOFF_W16   = WOFF_H + (size_t)NROWS*DE/2,
  WOFF_LAM   = WOFF_W16 + (HTOT_HALFS+1)/2,
  WOFF_LAML  = WOFF_LAM + (size_t)NBLKS*HH*2,
  WOFF_SL    = WOFF_LAML + (size_t)NBLKS*HH*2,
  WOFF_CARRY = WOFF_SL + (size_t)BB*NC32*HH*2,
  WOFF_STATS = WOFF_CARRY + (size_t)BB*NC32*HH*2,
  WOFF_POOL  = WOFF_STATS + (size_t)(NBLKS+1)*2*DE,
  WOFF_HL    = WOFF_POOL + (size_t)BB*DE,            // __half [B][128][32][512] local-scan states
  WS_FLOATS  = WOFF_HL + (size_t)BB*NC32*32*512/2
};

// ============================ prep ============================
__global__ __launch_bounds__(256) void k_prep(
    const float* __restrict__ nu_log, const float* __restrict__ theta_log,
    const float* __restrict__ B_re, const float* __restrict__ B_im,
    const float* __restrict__ C_re, const float* __restrict__ C_im,
    const float* __restrict__ W1g, const float* __restrict__ W2g,
    const float* __restrict__ Wenc, float* __restrict__ ws)
{
  const int i = blockIdx.x, h = threadIdx.x;
  __half* w16 = (__half*)(ws + WOFF_W16);
  const float nu  = expf(nu_log[i*HH+h]);
  const float th  = expf(theta_log[i*HH+h]);
  const float mod = expf(-nu);
  const float lr = mod*cosf(th), li = mod*sinf(th);
  const float gamma = sqrtf(fmaxf(1.0f - mod*mod, 1e-8f));
  ws[WOFF_LAM + ((size_t)i*HH+h)*2+0] = lr;
  ws[WOFF_LAM + ((size_t)i*HH+h)*2+1] = li;
  {
    float ar = lr, ai = li;
    #pragma unroll
    for (int q = 0; q < 5; q++) { float nr=ar*ar-ai*ai, ni=2.0f*ar*ai; ar=nr; ai=ni; }
    ws[WOFF_LAML + ((size_t)i*HH+h)*2+0] = ar;
    ws[WOFF_LAML + ((size_t)i*HH+h)*2+1] = ai;
  }
  // correction planes: A[t][h]=pr, A[t][256+h]=pi ; B[t][h]=-pi, B[t][256+h]=pr  (p = lam^(t+1))
  {
    __half* PA = w16 + HOFF_PA + (size_t)i*32*512;
    __half* PB = w16 + HOFF_PB + (size_t)i*32*512;
    float pr = lr, pi = li;
    for (int t = 0; t < 32; t++) {
      PA[(size_t)t*512 + h]       = __float2half(pr);
      PA[(size_t)t*512 + 256 + h] = __float2half(pi);
      PB[(size_t)t*512 + h]       = __float2half(-pi);
      PB[(size_t)t*512 + 256 + h] = __float2half(pr);
      const float nr = pr*lr - pi*li, ni = pr*li + pi*lr;
      pr = nr; pi = ni;
    }
  }
  {
    __half* bg = w16 + HOFF_BG + (size_t)i*512*128;
    const float* bre = B_re + ((size_t)i*HH+h)*DE;
    const float* bim = B_im + ((size_t)i*HH+h)*DE;
    for (int d = 0; d < DE; d++) {
      bg[(size_t)h*128 + d]       = __float2half(bre[d]*gamma);
      bg[(size_t)(256+h)*128 + d] = __float2half(bim[d]*gamma);
    }
  }
  {
    __half* wc = w16 + HOFF_WC + (size_t)i*128*512;
    const float* cre = C_re + (size_t)i*DE*HH;
    const float* cim = C_im + (size_t)i*DE*HH;
    for (int d = 0; d < DE; d++) {
      wc[(size_t)d*512 + h]       = __float2half( cre[(size_t)d*HH + h]);
      wc[(size_t)d*512 + 256 + h] = __float2half(-cim[(size_t)d*HH + h]);
    }
  }
  {
    __half* w1t = w16 + HOFF_W1 + (size_t)i*512*128;
    for (int d = 0; d < DE; d++) {
      w1t[(size_t)h*128 + d]       = __float2half(W1g[((size_t)i*DE + d)*LDIM + h]);
      w1t[(size_t)(256+h)*128 + d] = __float2half(W1g[((size_t)i*DE + d)*LDIM + 256 + h]);
    }
  }
  if (h < 128) {
    __half* w2t = w16 + HOFF_W2 + (size_t)i*128*256;
    for (int g = 0; g < 256; g++)
      w2t[(size_t)h*256 + g] = __float2half(W2g[((size_t)i*256 + g)*DE + h]);
  }
  if (i == 0 && h < 128) {
    __half* wet = w16 + HOFF_WE;
    for (int k = 0; k < TSZ; k++)
      wet[(size_t)h*TSZ + k] = __float2half(Wenc[(size_t)k*DE + h]);
  }
}

// ============================ encoder ============================
__global__ __launch_bounds__(512) void k_enc(
    const float* __restrict__ x, const float* __restrict__ benc, float* __restrict__ ws)
{
  __shared__ __half XT[64*72];
  __shared__ __half YS[64*136];
  const int tid = threadIdx.x, w = tid >> 6, l = tid & 63;
  const size_t row0 = (size_t)blockIdx.x * 64;
  {
    const float4* xg = (const float4*)(x + row0*TSZ);
    for (int idx = tid; idx < 1024; idx += 512) {
      float4 v = xg[idx];
      const int r = idx >> 4, c4 = (idx & 15)*4;
      *(__half2*)&XT[r*72 + c4]     = __half2{__float2half(v.x), __float2half(v.y)};
      *(__half2*)&XT[r*72 + c4 + 2] = __half2{__float2half(v.z), __float2half(v.w)};
    }
  }
  __syncthreads();
  const __half* wet = (const __half*)(ws + WOFF_W16) + HOFF_WE;
  const int n0 = w*16;
  f32x4 acc[4];
  #pragma unroll
  for (int mt = 0; mt < 4; mt++) acc[mt] = (f32x4)(0.0f);
  #pragma unroll
  for (int k0 = 0; k0 < 64; k0 += 32) {
    f16x8 bf = *(const f16x8*)&wet[(size_t)(n0 + (l&15))*64 + k0 + (l>>4)*8];
    #pragma unroll
    for (int mt = 0; mt < 4; mt++) {
      f16x8 af = *(const f16x8*)&XT[(mt*16 + (l&15))*72 + k0 + (l>>4)*8];
      acc[mt] = MFMA16(af, bf, acc[mt]);
    }
  }
  const int d = n0 + (l&15);
  const float be = benc[d];
  float s = 0.0f, ss = 0.0f;
  #pragma unroll
  for (int mt = 0; mt < 4; mt++)
    #pragma unroll
    for (int j = 0; j < 4; j++) {
      const int t = mt*16 + (l>>4)*4 + j;
      const float v = acc[mt][j] + be;
      YS[t*136 + d] = __float2half(v);
      s += v; ss += v*v;
    }
  s  += __shfl_xor(s, 16);  s  += __shfl_xor(s, 32);
  ss += __shfl_xor(ss, 16); ss += __shfl_xor(ss, 32);
  if (l < 16) {
    atomicAdd(ws + WOFF_STATS + d, s);
    atomicAdd(ws + WOFF_STATS + DE + d, ss);
  }
  __syncthreads();
  __half* y = (__half*)(ws + WOFF_Y);
  const int row = tid >> 3, d0 = (tid & 7)*16;
  *(f16x8*)&y[(row0+row)*DE + d0]     = *(const f16x8*)&YS[row*136 + d0];
  *(f16x8*)&y[(row0+row)*DE + d0 + 8] = *(const f16x8*)&YS[row*136 + d0 + 8];
}

// ============================ k_A: BN + B-proj + LDS scan -> HL(global) + SL ============================
__global__ __launch_bounds__(512, 4) void k_A(
    const __half* __restrict__ hin, float* __restrict__ ws,
    const float* __restrict__ bnsg, const float* __restrict__ bnbg, int iblk)
{
  __shared__ __half U[32*136];
  __shared__ __half BU[32*536];
  __shared__ float AC[256];
  const int tid = threadIdx.x, w = tid >> 6, l = tid & 63, q = l >> 4, r = l & 15;
  const int b = blockIdx.y, cbg = blockIdx.x;
  const int h = tid & 255;
  if (tid < 128) {
    const float inv = 1.0f / (float)NROWS;
    const float s  = ws[WOFF_STATS + ((size_t)iblk*2+0)*DE + tid];
    const float sq = ws[WOFF_STATS + ((size_t)iblk*2+1)*DE + tid];
    const float mean = s*inv;
    const float var  = sq*inv - mean*mean;
    const float a = rsqrtf(var + EPSF) * bnsg[iblk*DE + tid];
    AC[tid]       = a;
    AC[128 + tid] = bnbg[iblk*DE + tid] - mean*a;
  }
  const __half* BG = (const __half*)(ws + WOFF_W16) + HOFF_BG + (size_t)iblk*512*128;
  const int n0 = w*64;
  const float lr = ws[WOFF_LAM + ((size_t)iblk*HH+h)*2+0];
  const float li = ws[WOFF_LAM + ((size_t)iblk*HH+h)*2+1];
  f16x8 bg4[4][4];
  #pragma unroll
  for (int nt = 0; nt < 4; nt++)
    #pragma unroll
    for (int k = 0; k < 4; k++)
      bg4[nt][k] = *(const f16x8*)&BG[(size_t)(n0 + nt*16 + r)*128 + k*32 + q*8];
  __half* hlg = (__half*)(ws + WOFF_HL);
  __syncthreads();

  for (int it = 0; it < 4; it++) {
    const int cb = cbg*4 + it;
    const int row0 = b*TT + cb*32;
    // P1: BN -> U
    {
      const int row = tid >> 4, d0 = (tid & 15)*8;
      f16x8 hv = *(const f16x8*)(hin + (size_t)(row0+row)*DE + d0);
      f16x8 uv;
      #pragma unroll
      for (int j = 0; j < 8; j++)
        uv[j] = (_Float16)((float)hv[j]*AC[d0+j] + AC[128+d0+j]);
      *(f16x8*)&U[row*136 + d0] = uv;
    }
    __syncthreads();
    // P2: B-proj -> BU (LDS)
    {
      f32x4 acc[2][4];
      #pragma unroll
      for (int mt = 0; mt < 2; mt++)
        #pragma unroll
        for (int nt = 0; nt < 4; nt++) acc[mt][nt] = (f32x4)(0.0f);
      #pragma unroll
      for (int k = 0; k < 4; k++) {
        f16x8 af0 = *(const f16x8*)&U[(r)*136      + k*32 + q*8];
        f16x8 af1 = *(const f16x8*)&U[(16 + r)*136 + k*32 + q*8];
        #pragma unroll
        for (int nt = 0; nt < 4; nt++) {
          acc[0][nt] = MFMA16(af0, bg4[nt][k], acc[0][nt]);
          acc[1][nt] = MFMA16(af1, bg4[nt][k], acc[1][nt]);
        }
      }
      #pragma unroll
      for (int mt = 0; mt < 2; mt++)
        #pragma unroll
        for (int nt = 0; nt < 4; nt++)
          #pragma unroll
          for (int j = 0; j < 4; j++)
            BU[(mt*16 + q*4 + j)*536 + n0 + nt*16 + r] = __float2half(acc[mt][nt][j]);
    }
    __syncthreads();
    // P3: in-place 32-step local scan (zero init) + SL
    if (tid < 256) {
      float sr = 0.0f, si = 0.0f;
      #pragma unroll
      for (int t = 0; t < 32; t++) {
        const float br = (float)BU[t*536 + h];
        const float bi = (float)BU[t*536 + 256 + h];
        const float nr = lr*sr - li*si + br;
        const float ni = lr*si + li*sr + bi;
        sr = nr; si = ni;
        BU[t*536 + h]       = __float2half(sr);
        BU[t*536 + 256 + h] = __float2half(si);
      }
      *((float2*)(ws + WOFF_SL) + ((size_t)b*NC32 + cb)*HH + h) = float2{sr, si};
    }
    __syncthreads();
    // P4: coalesced write HL[b][cb][t][512]
    {
      __half* dst = hlg + ((size_t)(b*NC32 + cb)*32)*512;
      #pragma unroll
      for (int g = 0; g < 4; g++) {
        const int idx = tid + g*512;
        const int row = idx >> 6, col = (idx & 63)*8;
        *(f16x8*)(dst + (size_t)row*512 + col) = *(const f16x8*)&BU[row*536 + col];
      }
    }
    __syncthreads();
  }
}

// ============================ k_carry ============================
__global__ void k_carry(float* __restrict__ ws, int i)
{
  const int b = blockIdx.x >> 2;
  const int h = (blockIdx.x & 3)*64 + threadIdx.x;
  const float Lr = ws[WOFF_LAML + ((size_t)i*HH+h)*2+0];
  const float Li = ws[WOFF_LAML + ((size_t)i*HH+h)*2+1];
  float2* C = (float2*)(ws + WOFF_CARRY) + (size_t)b*NC32*HH + h;
  const float2* S = (const float2*)(ws + WOFF_SL) + (size_t)b*NC32*HH + h;
  float sr = 0.0f, si = 0.0f;
  C[0] = float2{0.0f, 0.0f};
  for (int c0 = 0; c0 < 120; c0 += 8) {
    float2 sl[8];
    #pragma unroll
    for (int j = 0; j < 8; j++) sl[j] = S[(size_t)(c0+j)*HH];
    #pragma unroll
    for (int j = 0; j < 8; j++) {
      const float nr = Lr*sr - Li*si + sl[j].x;
      const float ni = Lr*si + Li*sr + sl[j].y;
      sr = nr; si = ni;
      C[(size_t)(c0+j+1)*HH] = float2{sr, si};
    }
  }
  {
    float2 sl[7];
    #pragma unroll
    for (int j = 0; j < 7; j++) sl[j] = S[(size_t)(120+j)*HH];
    #pragma unroll
    for (int j = 0; j < 7; j++) {
      const float nr = Lr*sr - Li*si + sl[j].x;
      const float ni = Lr*si + Li*sr + sl[j].y;
      sr = nr; si = ni;
      C[(size_t)(121+j)*HH] = float2{sr, si};
    }
  }
}

// ============================ k_BC: stateless staging + C-proj + MLP ============================
__global__ __launch_bounds__(512, 4) void k_BC(
    const __half* __restrict__ hin, float* __restrict__ ws,
    const float* __restrict__ bnsg, const float* __restrict__ bnbg,
    const float* __restrict__ b1g, const float* __restrict__ b2g,
    const float* __restrict__ Dvg, int iblk, int islast)
{
  __shared__ __half U[32*136];     // u (BN'd) -> y (P3) -> h' (P4)
  __shared__ __half HT[32*520];    // h (corrected) -> G
  __shared__ __half YL[32*136];
  __shared__ float AC[256];
  __shared__ float DVs[128];
  const int tid = threadIdx.x, w = tid >> 6, l = tid & 63, q = l >> 4, r = l & 15;
  const int b = blockIdx.y, cbg = blockIdx.x;    // 32 groups × 4 chunks
  const __half* w16 = (const __half*)(ws + WOFF_W16);
  const int d = w*16 + r;

  if (tid < 128) {
    const float inv = 1.0f / (float)NROWS;
    const float s  = ws[WOFF_STATS + ((size_t)iblk*2+0)*DE + tid];
    const float sq = ws[WOFF_STATS + ((size_t)iblk*2+1)*DE + tid];
    const float mean = s*inv;
    const float var  = sq*inv - mean*mean;
    const float a = rsqrtf(var + EPSF) * bnsg[iblk*DE + tid];
    AC[tid]       = a;
    AC[128 + tid] = bnbg[iblk*DE + tid] - mean*a;
    DVs[tid] = Dvg[iblk*DE + tid];
  }

  // tile-invariant: correction planes for this thread's 4 (row,col) slots
  const __half* PA = w16 + HOFF_PA + (size_t)iblk*32*512;
  const __half* PB = w16 + HOFF_PB + (size_t)iblk*32*512;
  f16x8 pa[4], pb[4];
  #pragma unroll
  for (int g = 0; g < 4; g++) {
    const int idx = tid + g*512;
    const int row = idx >> 6, col = (idx & 63)*8;
    pa[g] = *(const f16x8*)&PA[(size_t)row*512 + col];
    pb[g] = *(const f16x8*)&PB[(size_t)row*512 + col];
  }
  const float bb2 = b2g[(size_t)iblk*DE + d];
  const __half* WC  = w16 + HOFF_WC + (size_t)iblk*128*512;
  const __half* W1T = w16 + HOFF_W1 + (size_t)iblk*512*128;
  const __half* W2T = w16 + HOFF_W2 + (size_t)iblk*128*256;
  const __half* hlg = (const __half*)(ws + WOFF_HL);
  const __half* yh = (const __half*)(ws + WOFF_Y);
  __half* hh = (__half*)(ws + WOFF_H);
  float s_acc = 0.0f, ss_acc = 0.0f;
  __syncthreads();

  for (int it = 0; it < 4; it++) {
    const int cb = cbg*4 + it;
    const int row0 = b*TT + cb*32;

    // ---- P1: stage h = l + A*cr + B*ci -> HT ; BN(hin) -> U ----
    {
      const int row = tid >> 4, d0 = (tid & 15)*8;
      f16x8 hv = *(const f16x8*)(hin + (size_t)(row0+row)*DE + d0);
      f16x8 uv;
      #pragma unroll
      for (int j = 0; j < 8; j++)
        uv[j] = (_Float16)((float)hv[j]*AC[d0+j] + AC[128+d0+j]);
      *(f16x8*)&U[row*136 + d0] = uv;
    }
    {
      const __half* src = hlg + ((size_t)(b*NC32 + cb)*32)*512;
      const float* cg = ws + WOFF_CARRY + ((size_t)b*NC32 + cb)*HH*2;
      #pragma unroll
      for (int g = 0; g < 4; g++) {
        const int idx = tid + g*512;
        const int row = idx >> 6, col = (idx & 63)*8;
        const int h0 = col & 255;
        f16x8 lv = *(const f16x8*)(src + (size_t)row*512 + col);
        float4 c0 = *(const float4*)(cg + h0*2);
        float4 c1 = *(const float4*)(cg + h0*2 + 4);
        float4 c2 = *(const float4*)(cg + h0*2 + 8);
        float4 c3 = *(const float4*)(cg + h0*2 + 12);
        const float cr[8] = {c0.x, c0.z, c1.x, c1.z, c2.x, c2.z, c3.x, c3.z};
        const float ci[8] = {c0.y, c0.w, c1.y, c1.w, c2.y, c2.w, c3.y, c3.w};
        f16x8 hv;
        #pragma unroll
        for (int j = 0; j < 8; j++)
          hv[j] = (_Float16)((float)lv[j] + (float)pa[g][j]*cr[j] + (float)pb[g][j]*ci[j]);
        *(f16x8*)&HT[row*520 + col] = hv;
      }
    }
    __syncthreads();

    // ---- P2: C-proj (K=512) + u*D -> YL ----
    {
      f32x4 a0 = (f32x4)(0.0f), a1 = (f32x4)(0.0f);
      #pragma unroll
      for (int kb = 0; kb < 2; kb++) {
        f16x8 wc[8];
        #pragma unroll
        for (int k = 0; k < 8; k++)
          wc[k] = *(const f16x8*)&WC[(size_t)d*512 + kb*256 + k*32 + q*8];
        #pragma unroll
        for (int k = 0; k < 8; k++) {
          f16x8 af0 = *(const f16x8*)&HT[(r)*520      + kb*256 + k*32 + q*8];
          f16x8 af1 = *(const f16x8*)&HT[(16 + r)*520 + kb*256 + k*32 + q*8];
          a0 = MFMA16(af0, wc[k], a0);
          a1 = MFMA16(af1, wc[k], a1);
        }
      }
      const float dv = DVs[d];
      #pragma unroll
      for (int mt = 0; mt < 2; mt++)
        #pragma unroll
        for (int j = 0; j < 4; j++) {
          const int t = mt*16 + q*4 + j;
          const float u = (float)U[t*136 + d];
          YL[t*136 + d] = __float2half((mt ? a1[j] : a0[j]) + u*dv);
        }
    }
    __syncthreads();

    // ---- P3: y -> U (u dead); W1 + GLU -> HT cols 0..255 ----
    {
      const int row = tid >> 4, d0 = (tid & 15)*8;
      *(f16x8*)&U[row*136 + d0] = *(const f16x8*)(yh + (size_t)(row0+row)*DE + d0);
    }
    #pragma unroll
    for (int nt = 0; nt < 2; nt++) {
      const int ca = w*32 + nt*16 + r;
      f16x8 wa[4], wb[4];
      #pragma unroll
      for (int k = 0; k < 4; k++) {
        wa[k] = *(const f16x8*)&W1T[(size_t)ca*128 + k*32 + q*8];
        wb[k] = *(const f16x8*)&W1T[(size_t)(256+ca)*128 + k*32 + q*8];
      }
      f32x4 aa0 = (f32x4)(0.0f), aa1 = (f32x4)(0.0f);
      f32x4 ab0 = (f32x4)(0.0f), ab1 = (f32x4)(0.0f);
      #pragma unroll
      for (int k = 0; k < 4; k++) {
        f16x8 af0 = *(const f16x8*)&YL[(r)*136      + k*32 + q*8];
        f16x8 af1 = *(const f16x8*)&YL[(16 + r)*136 + k*32 + q*8];
        aa0 = MFMA16(af0, wa[k], aa0);
        aa1 = MFMA16(af1, wa[k], aa1);
        ab0 = MFMA16(af0, wb[k], ab0);
        ab1 = MFMA16(af1, wb[k], ab1);
      }
      const float b1a = b1g[(size_t)iblk*LDIM + ca];
      const float b1b = b1g[(size_t)iblk*LDIM + 256 + ca];
      #pragma unroll
      for (int mt = 0; mt < 2; mt++)
        #pragma unroll
        for (int j = 0; j < 4; j++) {
          const int t = mt*16 + q*4 + j;
          const float av = (mt ? aa1[j] : aa0[j]) + b1a;
          const float bv = (mt ? ab1[j] : ab0[j]) + b1b;
          HT[t*520 + ca] = __float2half(av / (1.0f + __expf(-bv)));
        }
    }
    __syncthreads();

    // ---- P4: h' = G @ W2 + b2 + y(U) -> U, stats ----
    {
      f16x8 w2f[8];
      #pragma unroll
      for (int k = 0; k < 8; k++)
        w2f[k] = *(const f16x8*)&W2T[(size_t)d*256 + k*32 + q*8];
      f32x4 a0 = (f32x4)(0.0f), a1 = (f32x4)(0.0f);
      #pragma unroll
      for (int k = 0; k < 8; k++) {
        f16x8 af0 = *(const f16x8*)&HT[(r)*520      + k*32 + q*8];
        f16x8 af1 = *(const f16x8*)&HT[(16 + r)*520 + k*32 + q*8];
        a0 = MFMA16(af0, w2f[k], a0);
        a1 = MFMA16(af1, w2f[k], a1);
      }
      #pragma unroll
      for (int mt = 0; mt < 2; mt++)
        #pragma unroll
        for (int j = 0; j < 4; j++) {
          const int t = mt*16 + q*4 + j;
          const float v = (mt ? a1[j] : a0[j]) + bb2 + (float)U[t*136 + d];
          U[t*136 + d] = __float2half(v);
          s_acc += v; ss_acc += v*v;
        }
    }
    __syncthreads();

    // ---- P5: coalesced writeback ----
    {
      const int row = tid >> 4, d0 = (tid & 15)*8;
      *(f16x8*)(hh + (size_t)(row0+row)*DE + d0) = *(const f16x8*)&U[row*136 + d0];
    }
    __syncthreads();
  }

  s_acc  += __shfl_xor(s_acc, 16);  s_acc  += __shfl_xor(s_acc, 32);
  ss_acc += __shfl_xor(ss_acc, 16); ss_acc += __shfl_xor(ss_acc, 32);
  if (l < 16) {
    atomicAdd(ws + WOFF_STATS + (size_t)((iblk+1)*2 + 0)*DE + d, s_acc);
    atomicAdd(ws + WOFF_STATS + (size_t)((iblk+1)*2 + 1)*DE + d, ss_acc);
    if (islast) atomicAdd(ws + WOFF_POOL + (size_t)b*DE + d, s_acc);
  }
}

// ============================ final projection ============================
__global__ void k_out(const float* __restrict__ Wout, const float* __restrict__ bout,
                      const float* __restrict__ ws, float* __restrict__ out)
{
  const int tid = threadIdx.x;
  if (tid < BB*ODIM) {
    const int b = tid / ODIM, o = tid % ODIM;
    float acc = bout[o];
    const float* p = ws + WOFF_POOL + (size_t)b*DE;
    const float invT = 1.0f / (float)TT;
    for (int d = 0; d < DE; d++) acc += p[d]*invT*Wout[d*ODIM + o];
    out[tid] = acc;
  }
}

extern "C" void kernel_launch(void* const* d_in, const int* in_sizes, int n_in,
                              void* d_out, int out_size, void* d_ws, size_t ws_size,
                              hipStream_t stream)
{
  const float* x   = (const float*)d_in[0];
  const float* nu  = (const float*)d_in[1];
  const float* th  = (const float*)d_in[2];
  const float* Bre = (const float*)d_in[3];
  const float* Bim = (const float*)d_in[4];
  const float* Cre = (const float*)d_in[5];
  const float* Cim = (const float*)d_in[6];
  const float* Dv  = (const float*)d_in[7];
  const float* W1  = (const float*)d_in[8];
  const float* b1  = (const float*)d_in[9];
  const float* W2  = (const float*)d_in[10];
  const float* b2  = (const float*)d_in[11];
  const float* bns = (const float*)d_in[12];
  const float* bnb = (const float*)d_in[13];
  const float* We  = (const float*)d_in[14];
  const float* be  = (const float*)d_in[15];
  const float* Wo  = (const float*)d_in[16];
  const float* bo  = (const float*)d_in[17];
  float* ws = (float*)d_ws;
  float* out = (float*)d_out;

  hipMemsetAsync(ws + WOFF_STATS, 0,
                 (size_t)(((NBLKS+1)*2*DE) + BB*DE)*sizeof(float), stream);

  k_prep<<<NBLKS, 256, 0, stream>>>(nu, th, Bre, Bim, Cre, Cim, W1, W2, We, ws);
  k_enc<<<NROWS/64, 512, 0, stream>>>(x, be, ws);

  const __half* Yh = (const __half*)(ws + WOFF_Y);
  const __half* Hh = (const __half*)(ws + WOFF_H);
  for (int i = 0; i < NBLKS; i++) {
    const __half* hin = (i == 0) ? Yh : Hh;
    k_A    <<<dim3(32, BB), 512, 0, stream>>>(hin, ws, bns, bnb, i);
    k_carry<<<64, 64, 0, stream>>>(ws, i);
    k_BC   <<<dim3(32, BB), 512, 0, stream>>>(hin, ws, bns, bnb, b1, b2, Dv, i,
                                              (i == NBLKS-1) ? 1 : 0);
  }
  k_out<<<1, 256, 0, stream>>>(Wo, bo, ws, out);
}

// Round 15
// 833.825 us; speedup vs baseline: 1.3950x; 1.3950x over previous
//
#include <hip/hip_runtime.h>
#include <hip/hip_fp16.h>

#define BB 16
#define TT 4096
#define TSZ 64
#define DE 128
#define HH 256
#define LDIM 512
#define ODIM 10
#define NBLKS 6
#define EPSF 1e-5f
#define NC32 128          // 32-token chunks
#define NROWS (BB*TT)     // 65536

typedef _Float16 f16x8 __attribute__((ext_vector_type(8)));
typedef _Float16 f16x4 __attribute__((ext_vector_type(4)));
typedef float f32x4 __attribute__((ext_vector_type(4)));
#define MFMA16(a,b,c) __builtin_amdgcn_mfma_f32_16x16x32_f16((a),(b),(c),0,0,0)

// ---- f16 weight region layout ----
enum : size_t {
  HOFF_BG = 0,                                  // [NBLK][512][128]
  HOFF_WC = HOFF_BG + (size_t)NBLKS*512*128,    // [NBLK][128][512]  [d][h]=Cre, [d][256+h]=-Cim
  HOFF_W1 = HOFF_WC + (size_t)NBLKS*128*512,    // [NBLK][512][128]
  HOFF_W2 = HOFF_W1 + (size_t)NBLKS*512*128,    // [NBLK][128][256]
  HOFF_WE = HOFF_W2 + (size_t)NBLKS*128*256,    // [128][64]
  HTOT_HALFS = HOFF_WE + 128*64
};

// ---- workspace layout (float offsets) ----
enum : size_t {
  WOFF_Y     = 0,
  WOFF_H     = WOFF_Y + (size_t)NROWS*DE/2,
  WOFF_W16   = WOFF_H + (size_t)NROWS*DE/2,
  WOFF_LAM   = WOFF_W16 + (HTOT_HALFS+1)/2,
  WOFF_LAML  = WOFF_LAM + (size_t)NBLKS*HH*2,
  WOFF_SL    = WOFF_LAML + (size_t)NBLKS*HH*2,
  WOFF_CARRY = WOFF_SL + (size_t)BB*NC32*HH*2,
  WOFF_STATS = WOFF_CARRY + (size_t)BB*NC32*HH*2,
  WOFF_POOL  = WOFF_STATS + (size_t)(NBLKS+1)*2*DE,
  WOFF_BU    = WOFF_POOL + (size_t)BB*DE,            // __half [B][128][512][32]
  WS_FLOATS  = WOFF_BU + (size_t)BB*NC32*512*32/2
};

// LDS strides (halfs)
#define SU 152
#define SH 280

// ============================ prep ============================
__global__ __launch_bounds__(256) void k_prep(
    const float* __restrict__ nu_log, const float* __restrict__ theta_log,
    const float* __restrict__ B_re, const float* __restrict__ B_im,
    const float* __restrict__ C_re, const float* __restrict__ C_im,
    const float* __restrict__ W1g, const float* __restrict__ W2g,
    const float* __restrict__ Wenc, float* __restrict__ ws)
{
  const int i = blockIdx.x, h = threadIdx.x;
  __half* w16 = (__half*)(ws + WOFF_W16);
  const float nu  = expf(nu_log[i*HH+h]);
  const float th  = expf(theta_log[i*HH+h]);
  const float mod = expf(-nu);
  const float lr = mod*cosf(th), li = mod*sinf(th);
  const float gamma = sqrtf(fmaxf(1.0f - mod*mod, 1e-8f));
  ws[WOFF_LAM + ((size_t)i*HH+h)*2+0] = lr;
  ws[WOFF_LAM + ((size_t)i*HH+h)*2+1] = li;
  {
    float ar = lr, ai = li;
    #pragma unroll
    for (int q = 0; q < 5; q++) { float nr=ar*ar-ai*ai, ni=2.0f*ar*ai; ar=nr; ai=ni; }
    ws[WOFF_LAML + ((size_t)i*HH+h)*2+0] = ar;
    ws[WOFF_LAML + ((size_t)i*HH+h)*2+1] = ai;
  }
  {
    __half* bg = w16 + HOFF_BG + (size_t)i*512*128;
    const float* bre = B_re + ((size_t)i*HH+h)*DE;
    const float* bim = B_im + ((size_t)i*HH+h)*DE;
    for (int d = 0; d < DE; d++) {
      bg[(size_t)h*128 + d]       = __float2half(bre[d]*gamma);
      bg[(size_t)(256+h)*128 + d] = __float2half(bim[d]*gamma);
    }
  }
  {
    __half* wc = w16 + HOFF_WC + (size_t)i*128*512;
    const float* cre = C_re + (size_t)i*DE*HH;
    const float* cim = C_im + (size_t)i*DE*HH;
    for (int d = 0; d < DE; d++) {
      wc[(size_t)d*512 + h]       = __float2half( cre[(size_t)d*HH + h]);
      wc[(size_t)d*512 + 256 + h] = __float2half(-cim[(size_t)d*HH + h]);
    }
  }
  {
    __half* w1t = w16 + HOFF_W1 + (size_t)i*512*128;
    for (int d = 0; d < DE; d++) {
      w1t[(size_t)h*128 + d]       = __float2half(W1g[((size_t)i*DE + d)*LDIM + h]);
      w1t[(size_t)(256+h)*128 + d] = __float2half(W1g[((size_t)i*DE + d)*LDIM + 256 + h]);
    }
  }
  if (h < 128) {
    __half* w2t = w16 + HOFF_W2 + (size_t)i*128*256;
    for (int g = 0; g < 256; g++)
      w2t[(size_t)h*256 + g] = __float2half(W2g[((size_t)i*256 + g)*DE + h]);
  }
  if (i == 0 && h < 128) {
    __half* wet = w16 + HOFF_WE;
    for (int k = 0; k < TSZ; k++)
      wet[(size_t)h*TSZ + k] = __float2half(Wenc[(size_t)k*DE + h]);
  }
}

// ============================ encoder ============================
__global__ __launch_bounds__(512) void k_enc(
    const float* __restrict__ x, const float* __restrict__ benc, float* __restrict__ ws)
{
  __shared__ __half XT[64*72];
  __shared__ __half YS[64*136];
  const int tid = threadIdx.x, w = tid >> 6, l = tid & 63;
  const size_t row0 = (size_t)blockIdx.x * 64;
  {
    const float4* xg = (const float4*)(x + row0*TSZ);
    for (int idx = tid; idx < 1024; idx += 512) {
      float4 v = xg[idx];
      const int r = idx >> 4, c4 = (idx & 15)*4;
      *(__half2*)&XT[r*72 + c4]     = __half2{__float2half(v.x), __float2half(v.y)};
      *(__half2*)&XT[r*72 + c4 + 2] = __half2{__float2half(v.z), __float2half(v.w)};
    }
  }
  __syncthreads();
  const __half* wet = (const __half*)(ws + WOFF_W16) + HOFF_WE;
  const int n0 = w*16;
  f32x4 acc[4];
  #pragma unroll
  for (int mt = 0; mt < 4; mt++) acc[mt] = (f32x4)(0.0f);
  #pragma unroll
  for (int k0 = 0; k0 < 64; k0 += 32) {
    f16x8 bf = *(const f16x8*)&wet[(size_t)(n0 + (l&15))*64 + k0 + (l>>4)*8];
    #pragma unroll
    for (int mt = 0; mt < 4; mt++) {
      f16x8 af = *(const f16x8*)&XT[(mt*16 + (l&15))*72 + k0 + (l>>4)*8];
      acc[mt] = MFMA16(af, bf, acc[mt]);
    }
  }
  const int d = n0 + (l&15);
  const float be = benc[d];
  float s = 0.0f, ss = 0.0f;
  #pragma unroll
  for (int mt = 0; mt < 4; mt++)
    #pragma unroll
    for (int j = 0; j < 4; j++) {
      const int t = mt*16 + (l>>4)*4 + j;
      const float v = acc[mt][j] + be;
      YS[t*136 + d] = __float2half(v);
      s += v; ss += v*v;
    }
  s  += __shfl_xor(s, 16);  s  += __shfl_xor(s, 32);
  ss += __shfl_xor(ss, 16); ss += __shfl_xor(ss, 32);
  if (l < 16) {
    atomicAdd(ws + WOFF_STATS + d, s);
    atomicAdd(ws + WOFF_STATS + DE + d, ss);
  }
  __syncthreads();
  __half* y = (__half*)(ws + WOFF_Y);
  const int row = tid >> 3, d0 = (tid & 7)*16;
  *(f16x8*)&y[(row0+row)*DE + d0]     = *(const f16x8*)&YS[row*136 + d0];
  *(f16x8*)&y[(row0+row)*DE + d0 + 8] = *(const f16x8*)&YS[row*136 + d0 + 8];
}

// ============================ k_A: BN + B-proj -> Bu(global) + LDS scan -> SL ============================
__global__ __launch_bounds__(512, 4) void k_A(
    const __half* __restrict__ hin, float* __restrict__ ws,
    const float* __restrict__ bnsg, const float* __restrict__ bnbg, int iblk)
{
  __shared__ __half U[32*136];
  __shared__ __half BU[32*536];
  __shared__ float AC[256];
  const int tid = threadIdx.x, w = tid >> 6, l = tid & 63, q = l >> 4, r = l & 15;
  const int b = blockIdx.y, cbg = blockIdx.x;
  const int h = tid & 255;
  if (tid < 128) {
    const float inv = 1.0f / (float)NROWS;
    const float s  = ws[WOFF_STATS + ((size_t)iblk*2+0)*DE + tid];
    const float sq = ws[WOFF_STATS + ((size_t)iblk*2+1)*DE + tid];
    const float mean = s*inv;
    const float var  = sq*inv - mean*mean;
    const float a = rsqrtf(var + EPSF) * bnsg[iblk*DE + tid];
    AC[tid]       = a;
    AC[128 + tid] = bnbg[iblk*DE + tid] - mean*a;
  }
  const __half* BG = (const __half*)(ws + WOFF_W16) + HOFF_BG + (size_t)iblk*512*128;
  const int n0 = w*64;
  const float lr = ws[WOFF_LAM + ((size_t)iblk*HH+h)*2+0];
  const float li = ws[WOFF_LAM + ((size_t)iblk*HH+h)*2+1];
  f16x8 bg4[4][4];
  #pragma unroll
  for (int nt = 0; nt < 4; nt++)
    #pragma unroll
    for (int k = 0; k < 4; k++)
      bg4[nt][k] = *(const f16x8*)&BG[(size_t)(n0 + nt*16 + r)*128 + k*32 + q*8];
  __half* bug = (__half*)(ws + WOFF_BU);
  __syncthreads();

  for (int it = 0; it < 4; it++) {
    const int cb = cbg*4 + it;
    const int row0 = b*TT + cb*32;
    {
      const int row = tid >> 4, d0 = (tid & 15)*8;
      f16x8 hv = *(const f16x8*)(hin + (size_t)(row0+row)*DE + d0);
      f16x8 uv;
      #pragma unroll
      for (int j = 0; j < 8; j++)
        uv[j] = (_Float16)((float)hv[j]*AC[d0+j] + AC[128+d0+j]);
      *(f16x8*)&U[row*136 + d0] = uv;
    }
    __syncthreads();
    {
      f32x4 acc[2][4];
      #pragma unroll
      for (int mt = 0; mt < 2; mt++)
        #pragma unroll
        for (int nt = 0; nt < 4; nt++) acc[mt][nt] = (f32x4)(0.0f);
      #pragma unroll
      for (int k = 0; k < 4; k++) {
        f16x8 af0 = *(const f16x8*)&U[(r)*136      + k*32 + q*8];
        f16x8 af1 = *(const f16x8*)&U[(16 + r)*136 + k*32 + q*8];
        #pragma unroll
        for (int nt = 0; nt < 4; nt++) {
          acc[0][nt] = MFMA16(af0, bg4[nt][k], acc[0][nt]);
          acc[1][nt] = MFMA16(af1, bg4[nt][k], acc[1][nt]);
        }
      }
      #pragma unroll
      for (int mt = 0; mt < 2; mt++)
        #pragma unroll
        for (int nt = 0; nt < 4; nt++) {
          f16x4 pk;
          #pragma unroll
          for (int j = 0; j < 4; j++) {
            pk[j] = (_Float16)acc[mt][nt][j];
            BU[(mt*16 + q*4 + j)*536 + n0 + nt*16 + r] = __float2half(acc[mt][nt][j]);
          }
          const int hc = n0 + nt*16 + r;
          *(f16x4*)(bug + (((size_t)(b*NC32 + cb)*512 + hc)*32 + mt*16 + q*4)) = pk;
        }
    }
    __syncthreads();
    if (tid < 256) {
      float sr = 0.0f, si = 0.0f;
      #pragma unroll
      for (int t = 0; t < 32; t++) {
        const float br = (float)BU[t*536 + h];
        const float bi = (float)BU[t*536 + 256 + h];
        const float nr = lr*sr - li*si + br;
        const float ni = lr*si + li*sr + bi;
        sr = nr; si = ni;
      }
      *((float2*)(ws + WOFF_SL) + ((size_t)b*NC32 + cb)*HH + h) = float2{sr, si};
    }
    __syncthreads();
  }
}

// ============================ k_carry ============================
__global__ void k_carry(float* __restrict__ ws, int i)
{
  const int b = blockIdx.x >> 2;
  const int h = (blockIdx.x & 3)*64 + threadIdx.x;
  const float Lr = ws[WOFF_LAML + ((size_t)i*HH+h)*2+0];
  const float Li = ws[WOFF_LAML + ((size_t)i*HH+h)*2+1];
  float2* C = (float2*)(ws + WOFF_CARRY) + (size_t)b*NC32*HH + h;
  const float2* S = (const float2*)(ws + WOFF_SL) + (size_t)b*NC32*HH + h;
  float sr = 0.0f, si = 0.0f;
  C[0] = float2{0.0f, 0.0f};
  for (int c0 = 0; c0 < 120; c0 += 8) {
    float2 sl[8];
    #pragma unroll
    for (int j = 0; j < 8; j++) sl[j] = S[(size_t)(c0+j)*HH];
    #pragma unroll
    for (int j = 0; j < 8; j++) {
      const float nr = Lr*sr - Li*si + sl[j].x;
      const float ni = Lr*si + Li*sr + sl[j].y;
      sr = nr; si = ni;
      C[(size_t)(c0+j+1)*HH] = float2{sr, si};
    }
  }
  {
    float2 sl[7];
    #pragma unroll
    for (int j = 0; j < 7; j++) sl[j] = S[(size_t)(120+j)*HH];
    #pragma unroll
    for (int j = 0; j < 7; j++) {
      const float nr = Lr*sr - Li*si + sl[j].x;
      const float ni = Lr*si + Li*sr + sl[j].y;
      sr = nr; si = ni;
      C[(size_t)(121+j)*HH] = float2{sr, si};
    }
  }
}

// ============================ k_BC: M=64 tiles, re/im-split C-proj, no cross-barrier arrays ============================
__global__ __launch_bounds__(512, 2) void k_BC(
    const __half* __restrict__ hin, float* __restrict__ ws,
    const float* __restrict__ bnsg, const float* __restrict__ bnbg,
    const float* __restrict__ b1g, const float* __restrict__ b2g,
    const float* __restrict__ Dvg, int iblk, int islast)
{
  __shared__ __half U[64*SU];      // BN'd u -> (P3) residual y -> (P4) h' staging
  __shared__ __half HT[64*SH];     // scan re -> scan im -> G
  __shared__ __half YL[64*SU];
  __shared__ float AC[256];
  __shared__ float DVs[128];
  const int tid = threadIdx.x, w = tid >> 6, l = tid & 63, q = l >> 4, r = l & 15;
  const int b = blockIdx.y, cbg = blockIdx.x;    // 32 groups × 4 chunks (2 tiles of 64 rows)
  const __half* w16 = (const __half*)(ws + WOFF_W16);
  const int d = w*16 + r;
  const int h = tid & 255, cl = tid >> 8;        // scan job: chunk-local cl, channel h

  if (tid < 128) {
    const float inv = 1.0f / (float)NROWS;
    const float s  = ws[WOFF_STATS + ((size_t)iblk*2+0)*DE + tid];
    const float sq = ws[WOFF_STATS + ((size_t)iblk*2+1)*DE + tid];
    const float mean = s*inv;
    const float var  = sq*inv - mean*mean;
    const float a = rsqrtf(var + EPSF) * bnsg[iblk*DE + tid];
    AC[tid]       = a;
    AC[128 + tid] = bnbg[iblk*DE + tid] - mean*a;
    DVs[tid] = Dvg[iblk*DE + tid];
  }

  const float lr = ws[WOFF_LAM + ((size_t)iblk*HH+h)*2+0];
  const float li = ws[WOFF_LAM + ((size_t)iblk*HH+h)*2+1];
  float b1a[2], b1b[2];
  #pragma unroll
  for (int nt = 0; nt < 2; nt++) {
    const int ca = w*32 + nt*16 + r;
    b1a[nt] = b1g[(size_t)iblk*LDIM + ca];
    b1b[nt] = b1g[(size_t)iblk*LDIM + 256 + ca];
  }
  const float bb2 = b2g[(size_t)iblk*DE + d];
  const __half* WC  = w16 + HOFF_WC + (size_t)iblk*128*512;
  const __half* W1T = w16 + HOFF_W1 + (size_t)iblk*512*128;
  const __half* W2T = w16 + HOFF_W2 + (size_t)iblk*128*256;
  const __half* bug = (const __half*)(ws + WOFF_BU);
  const __half* yh = (const __half*)(ws + WOFF_Y);
  __half* hh = (__half*)(ws + WOFF_H);
  float s_acc = 0.0f, ss_acc = 0.0f;
  __syncthreads();

  for (int it = 0; it < 2; it++) {               // 2 tiles × 64 rows
    const int cb0 = cbg*4 + it*2;                // first chunk of tile
    const int row0 = b*TT + cb0*32;

    // ---- P1: coalesced hin load; BN -> U; scan (si in regs) -> HT ----
    {
      const int row = tid >> 3, d0 = (tid & 7)*16;
      const __half* hp = hin + (size_t)(row0+row)*DE + d0;
      f16x8 h0 = *(const f16x8*)hp, h1 = *(const f16x8*)(hp+8);
      f16x8 u0, u1;
      #pragma unroll
      for (int j = 0; j < 8; j++) {
        u0[j] = (_Float16)((float)h0[j]*AC[d0+j]   + AC[128+d0+j]);
        u1[j] = (_Float16)((float)h1[j]*AC[d0+8+j] + AC[128+d0+8+j]);
      }
      *(f16x8*)&U[row*SU + d0]     = u0;
      *(f16x8*)&U[row*SU + d0 + 8] = u1;
    }
    f16x8 si8[4];
    {
      const int cb = cb0 + cl;
      const __half* bu = bug + ((size_t)(b*NC32 + cb)*512)*32;
      f16x8 bre[4], bim[4];
      #pragma unroll
      for (int k = 0; k < 4; k++) {
        bre[k] = *(const f16x8*)(bu + (size_t)h*32 + k*8);
        bim[k] = *(const f16x8*)(bu + (size_t)(256+h)*32 + k*8);
      }
      const float2 carry = *((const float2*)(ws + WOFF_CARRY) + ((size_t)b*NC32 + cb)*HH + h);
      float sr = carry.x, si = carry.y;
      #pragma unroll
      for (int t = 0; t < 32; t++) {
        const float br = (float)bre[t>>3][t&7];
        const float bi = (float)bim[t>>3][t&7];
        const float nr = lr*sr - li*si + br;
        const float ni = lr*si + li*sr + bi;
        sr = nr; si = ni;
        HT[(cl*32 + t)*SH + h] = __float2half(sr);
        si8[t>>3][t&7] = (_Float16)si;
      }
    }
    __syncthreads();

    // ---- P2a: C-proj re-half (K=256) ----
    f32x4 acc[4];
    #pragma unroll
    for (int mt = 0; mt < 4; mt++) acc[mt] = (f32x4)(0.0f);
    {
      f16x8 wcre[8];
      #pragma unroll
      for (int k = 0; k < 8; k++)
        wcre[k] = *(const f16x8*)&WC[(size_t)d*512 + k*32 + q*8];
      #pragma unroll
      for (int k = 0; k < 8; k++)
        #pragma unroll
        for (int mt = 0; mt < 4; mt++) {
          f16x8 af = *(const f16x8*)&HT[(mt*16 + r)*SH + k*32 + q*8];
          acc[mt] = MFMA16(af, wcre[k], acc[mt]);
        }
    }
    __syncthreads();
    // ---- swap si into HT ----
    #pragma unroll
    for (int t = 0; t < 32; t++)
      HT[(cl*32 + t)*SH + h] = si8[t>>3][t&7];
    __syncthreads();
    // ---- P2b: C-proj im-half (K=256) + u*D -> YL ----
    {
      f16x8 wcim[8];
      #pragma unroll
      for (int k = 0; k < 8; k++)
        wcim[k] = *(const f16x8*)&WC[(size_t)d*512 + 256 + k*32 + q*8];
      #pragma unroll
      for (int k = 0; k < 8; k++)
        #pragma unroll
        for (int mt = 0; mt < 4; mt++) {
          f16x8 af = *(const f16x8*)&HT[(mt*16 + r)*SH + k*32 + q*8];
          acc[mt] = MFMA16(af, wcim[k], acc[mt]);
        }
      const float dv = DVs[d];
      #pragma unroll
      for (int mt = 0; mt < 4; mt++)
        #pragma unroll
        for (int j = 0; j < 4; j++) {
          const int t = mt*16 + q*4 + j;
          const float u = (float)U[t*SU + d];
          YL[t*SU + d] = __float2half(acc[mt][j] + u*dv);
        }
    }
    __syncthreads();

    // ---- P3: load y -> U (coalesced, u dead); W1 + GLU -> HT ----
    {
      const int row = tid >> 3, d0 = (tid & 7)*16;
      const __half* yp = yh + (size_t)(row0+row)*DE + d0;
      *(f16x8*)&U[row*SU + d0]     = *(const f16x8*)yp;
      *(f16x8*)&U[row*SU + d0 + 8] = *(const f16x8*)(yp+8);
    }
    {
      #pragma unroll
      for (int nt = 0; nt < 2; nt++) {
        const int ca = w*32 + nt*16 + r;
        f16x8 wa[4], wb[4];
        #pragma unroll
        for (int k = 0; k < 4; k++) {
          wa[k] = *(const f16x8*)&W1T[(size_t)ca*128 + k*32 + q*8];
          wb[k] = *(const f16x8*)&W1T[(size_t)(256+ca)*128 + k*32 + q*8];
        }
        f32x4 aa[4], ab[4];
        #pragma unroll
        for (int mt = 0; mt < 4; mt++) { aa[mt] = (f32x4)(0.0f); ab[mt] = (f32x4)(0.0f); }
        #pragma unroll
        for (int k = 0; k < 4; k++)
          #pragma unroll
          for (int mt = 0; mt < 4; mt++) {
            f16x8 af = *(const f16x8*)&YL[(mt*16 + r)*SU + k*32 + q*8];
            aa[mt] = MFMA16(af, wa[k], aa[mt]);
            ab[mt] = MFMA16(af, wb[k], ab[mt]);
          }
        #pragma unroll
        for (int mt = 0; mt < 4; mt++)
          #pragma unroll
          for (int j = 0; j < 4; j++) {
            const int t = mt*16 + q*4 + j;
            const float av = aa[mt][j] + b1a[nt];
            const float bv = ab[mt][j] + b1b[nt];
            HT[t*SH + ca] = __float2half(av / (1.0f + __expf(-bv)));
          }
      }
    }
    __syncthreads();

    // ---- P4: h' = G @ W2 + b2 + y(U) -> U, stats ----
    {
      f16x8 w2f[8];
      #pragma unroll
      for (int k = 0; k < 8; k++)
        w2f[k] = *(const f16x8*)&W2T[(size_t)d*256 + k*32 + q*8];
      f32x4 a2[4];
      #pragma unroll
      for (int mt = 0; mt < 4; mt++) a2[mt] = (f32x4)(0.0f);
      #pragma unroll
      for (int k = 0; k < 8; k++)
        #pragma unroll
        for (int mt = 0; mt < 4; mt++) {
          f16x8 af = *(const f16x8*)&HT[(mt*16 + r)*SH + k*32 + q*8];
          a2[mt] = MFMA16(af, w2f[k], a2[mt]);
        }
      #pragma unroll
      for (int mt = 0; mt < 4; mt++)
        #pragma unroll
        for (int j = 0; j < 4; j++) {
          const int t = mt*16 + q*4 + j;
          const float v = a2[mt][j] + bb2 + (float)U[t*SU + d];
          U[t*SU + d] = __float2half(v);
          s_acc += v; ss_acc += v*v;
        }
    }
    __syncthreads();

    // ---- P5: coalesced writeback ----
    {
      const int row = tid >> 3, d0 = (tid & 7)*16;
      *(f16x8*)(hh + (size_t)(row0+row)*DE + d0)     = *(const f16x8*)&U[row*SU + d0];
      *(f16x8*)(hh + (size_t)(row0+row)*DE + d0 + 8) = *(const f16x8*)&U[row*SU + d0 + 8];
    }
    __syncthreads();
  }

  s_acc  += __shfl_xor(s_acc, 16);  s_acc  += __shfl_xor(s_acc, 32);
  ss_acc += __shfl_xor(ss_acc, 16); ss_acc += __shfl_xor(ss_acc, 32);
  if (l < 16) {
    atomicAdd(ws + WOFF_STATS + (size_t)((iblk+1)*2 + 0)*DE + d, s_acc);
    atomicAdd(ws + WOFF_STATS + (size_t)((iblk+1)*2 + 1)*DE + d, ss_acc);
    if (islast) atomicAdd(ws + WOFF_POOL + (size_t)b*DE + d, s_acc);
  }
}

// ============================ final projection ============================
__global__ void k_out(const float* __restrict__ Wout, const float* __restrict__ bout,
                      const float* __restrict__ ws, float* __restrict__ out)
{
  const int tid = threadIdx.x;
  if (tid < BB*ODIM) {
    const int b = tid / ODIM, o = tid % ODIM;
    float acc = bout[o];
    const float* p = ws + WOFF_POOL + (size_t)b*DE;
    const float invT = 1.0f / (float)TT;
    for (int d = 0; d < DE; d++) acc += p[d]*invT*Wout[d*ODIM + o];
    out[tid] = acc;
  }
}

extern "C" void kernel_launch(void* const* d_in, const int* in_sizes, int n_in,
                              void* d_out, int out_size, void* d_ws, size_t ws_size,
                              hipStream_t stream)
{
  const float* x   = (const float*)d_in[0];
  const float* nu  = (const float*)d_in[1];
  const float* th  = (const float*)d_in[2];
  const float* Bre = (const float*)d_in[3];
  const float* Bim = (const float*)d_in[4];
  const float* Cre = (const float*)d_in[5];
  const float* Cim = (const float*)d_in[6];
  const float* Dv  = (const float*)d_in[7];
  const float* W1  = (const float*)d_in[8];
  const float* b1  = (const float*)d_in[9];
  const float* W2  = (const float*)d_in[10];
  const float* b2  = (const float*)d_in[11];
  const float* bns = (const float*)d_in[12];
  const float* bnb = (const float*)d_in[13];
  const float* We  = (const float*)d_in[14];
  const float* be  = (const float*)d_in[15];
  const float* Wo  = (const float*)d_in[16];
  const float* bo  = (const float*)d_in[17];
  float* ws = (float*)d_ws;
  float* out = (float*)d_out;

  hipMemsetAsync(ws + WOFF_STATS, 0,
                 (size_t)(((NBLKS+1)*2*DE) + BB*DE)*sizeof(float), stream);

  k_prep<<<NBLKS, 256, 0, stream>>>(nu, th, Bre, Bim, Cre, Cim, W1, W2, We, ws);
  k_enc<<<NROWS/64, 512, 0, stream>>>(x, be, ws);

  const __half* Yh = (const __half*)(ws + WOFF_Y);
  const __half* Hh = (const __half*)(ws + WOFF_H);
  for (int i = 0; i < NBLKS; i++) {
    const __half* hin = (i == 0) ? Yh : Hh;
    k_A    <<<dim3(32, BB), 512, 0, stream>>>(hin, ws, bns, bnb, i);
    k_carry<<<64, 64, 0, stream>>>(ws, i);
    k_BC   <<<dim3(32, BB), 512, 0, stream>>>(hin, ws, bns, bnb, b1, b2, Dv, i,
                                              (i == NBLKS-1) ? 1 : 0);
  }
  k_out<<<1, 256, 0, stream>>>(Wo, bo, ws, out);
}

// Round 16
// 773.523 us; speedup vs baseline: 1.5037x; 1.0780x over previous
//
#include <hip/hip_runtime.h>
#include <hip/hip_fp16.h>

#define BB 16
#define TT 4096
#define TSZ 64
#define DE 128
#define HH 256
#define LDIM 512
#define ODIM 10
#define NBLKS 6
#define EPSF 1e-5f
#define NC32 128          // 32-token chunks
#define NROWS (BB*TT)     // 65536

typedef _Float16 f16x8 __attribute__((ext_vector_type(8)));
typedef _Float16 f16x4 __attribute__((ext_vector_type(4)));
typedef float f32x4 __attribute__((ext_vector_type(4)));
#define MFMA16(a,b,c) __builtin_amdgcn_mfma_f32_16x16x32_f16((a),(b),(c),0,0,0)

// ---- f16 weight region layout ----
enum : size_t {
  HOFF_BG = 0,                                  // [NBLK][512][128]
  HOFF_WC = HOFF_BG + (size_t)NBLKS*512*128,    // [NBLK][128][512]  [d][h]=Cre, [d][256+h]=-Cim
  HOFF_W1 = HOFF_WC + (size_t)NBLKS*128*512,    // [NBLK][512][128]
  HOFF_W2 = HOFF_W1 + (size_t)NBLKS*512*128,    // [NBLK][128][256]
  HOFF_WE = HOFF_W2 + (size_t)NBLKS*128*256,    // [128][64]
  HTOT_HALFS = HOFF_WE + 128*64
};

// ---- workspace layout (float offsets) ----
enum : size_t {
  WOFF_Y     = 0,
  WOFF_H     = WOFF_Y + (size_t)NROWS*DE/2,
  WOFF_W16   = WOFF_H + (size_t)NROWS*DE/2,
  WOFF_LAM   = WOFF_W16 + (HTOT_HALFS+1)/2,
  WOFF_LAML  = WOFF_LAM + (size_t)NBLKS*HH*2,
  WOFF_SL    = WOFF_LAML + (size_t)NBLKS*HH*2,
  WOFF_CARRY = WOFF_SL + (size_t)BB*NC32*HH*2,
  WOFF_STATS = WOFF_CARRY + (size_t)BB*NC32*HH*2,
  WOFF_POOL  = WOFF_STATS + (size_t)(NBLKS+1)*2*DE,
  WOFF_BU    = WOFF_POOL + (size_t)BB*DE,            // __half [B][128][512][32]
  WS_FLOATS  = WOFF_BU + (size_t)BB*NC32*512*32/2
};

// LDS strides (halfs)
#define SU 152
#define SH 280

// ============================ prep (16-way sliced) ============================
__global__ __launch_bounds__(256) void k_prep(
    const float* __restrict__ nu_log, const float* __restrict__ theta_log,
    const float* __restrict__ B_re, const float* __restrict__ B_im,
    const float* __restrict__ C_re, const float* __restrict__ C_im,
    const float* __restrict__ W1g, const float* __restrict__ W2g,
    const float* __restrict__ Wenc, float* __restrict__ ws)
{
  const int i = blockIdx.x, s = blockIdx.y, h = threadIdx.x;
  __half* w16 = (__half*)(ws + WOFF_W16);
  const float nu  = expf(nu_log[i*HH+h]);
  const float th  = expf(theta_log[i*HH+h]);
  const float mod = expf(-nu);
  const float gamma = sqrtf(fmaxf(1.0f - mod*mod, 1e-8f));

  if (s == 0) {
    const float lr = mod*cosf(th), li = mod*sinf(th);
    ws[WOFF_LAM + ((size_t)i*HH+h)*2+0] = lr;
    ws[WOFF_LAM + ((size_t)i*HH+h)*2+1] = li;
    float ar = lr, ai = li;
    #pragma unroll
    for (int q = 0; q < 5; q++) { float nr=ar*ar-ai*ai, ni=2.0f*ar*ai; ar=nr; ai=ni; }
    ws[WOFF_LAML + ((size_t)i*HH+h)*2+0] = ar;
    ws[WOFF_LAML + ((size_t)i*HH+h)*2+1] = ai;
    if (i == 0 && h < 128) {
      __half* wet = w16 + HOFF_WE;
      for (int k = 0; k < TSZ; k++)
        wet[(size_t)h*TSZ + k] = __float2half(Wenc[(size_t)k*DE + h]);
    }
  }

  const int d0 = s*8;      // 8 d-rows per slice
  // BG [512][128]: rows h (re), 256+h (im), cols d0..d0+7 — vector stores
  {
    __half* bg = w16 + HOFF_BG + (size_t)i*512*128;
    const float* bre = B_re + ((size_t)i*HH+h)*DE + d0;
    const float* bim = B_im + ((size_t)i*HH+h)*DE + d0;
    f16x8 vr, vi;
    #pragma unroll
    for (int j = 0; j < 8; j++) {
      vr[j] = (_Float16)(bre[j]*gamma);
      vi[j] = (_Float16)(bim[j]*gamma);
    }
    *(f16x8*)&bg[(size_t)h*128 + d0]       = vr;
    *(f16x8*)&bg[(size_t)(256+h)*128 + d0] = vi;
  }
  // WC [128][512]: rows d0..d0+7, coalesced across h
  {
    __half* wc = w16 + HOFF_WC + (size_t)i*128*512;
    const float* cre = C_re + (size_t)i*DE*HH;
    const float* cim = C_im + (size_t)i*DE*HH;
    #pragma unroll
    for (int j = 0; j < 8; j++) {
      const int d = d0 + j;
      wc[(size_t)d*512 + h]       = __float2half( cre[(size_t)d*HH + h]);
      wc[(size_t)d*512 + 256 + h] = __float2half(-cim[(size_t)d*HH + h]);
    }
  }
  // W1T [512][128]: rows h (lo), 256+h (hi), cols d0..d0+7 — vector stores
  {
    __half* w1t = w16 + HOFF_W1 + (size_t)i*512*128;
    f16x8 v0, v1;
    #pragma unroll
    for (int j = 0; j < 8; j++) {
      v0[j] = (_Float16)W1g[((size_t)i*DE + d0 + j)*LDIM + h];
      v1[j] = (_Float16)W1g[((size_t)i*DE + d0 + j)*LDIM + 256 + h];
    }
    *(f16x8*)&w1t[(size_t)h*128 + d0]       = v0;
    *(f16x8*)&w1t[(size_t)(256+h)*128 + d0] = v1;
  }
  // W2T [128][256]: h<128 rows, g slice of 16 — two vector stores
  if (h < 128) {
    __half* w2t = w16 + HOFF_W2 + (size_t)i*128*256;
    const int g0 = s*16;
    f16x8 v0, v1;
    #pragma unroll
    for (int j = 0; j < 8; j++) {
      v0[j] = (_Float16)W2g[((size_t)i*256 + g0 + j)*DE + h];
      v1[j] = (_Float16)W2g[((size_t)i*256 + g0 + 8 + j)*DE + h];
    }
    *(f16x8*)&w2t[(size_t)h*256 + g0]     = v0;
    *(f16x8*)&w2t[(size_t)h*256 + g0 + 8] = v1;
  }
}

// ============================ encoder ============================
__global__ __launch_bounds__(512) void k_enc(
    const float* __restrict__ x, const float* __restrict__ benc, float* __restrict__ ws)
{
  __shared__ __half XT[64*72];
  __shared__ __half YS[64*136];
  const int tid = threadIdx.x, w = tid >> 6, l = tid & 63;
  const size_t row0 = (size_t)blockIdx.x * 64;
  {
    const float4* xg = (const float4*)(x + row0*TSZ);
    for (int idx = tid; idx < 1024; idx += 512) {
      float4 v = xg[idx];
      const int r = idx >> 4, c4 = (idx & 15)*4;
      *(__half2*)&XT[r*72 + c4]     = __half2{__float2half(v.x), __float2half(v.y)};
      *(__half2*)&XT[r*72 + c4 + 2] = __half2{__float2half(v.z), __float2half(v.w)};
    }
  }
  __syncthreads();
  const __half* wet = (const __half*)(ws + WOFF_W16) + HOFF_WE;
  const int n0 = w*16;
  f32x4 acc[4];
  #pragma unroll
  for (int mt = 0; mt < 4; mt++) acc[mt] = (f32x4)(0.0f);
  #pragma unroll
  for (int k0 = 0; k0 < 64; k0 += 32) {
    f16x8 bf = *(const f16x8*)&wet[(size_t)(n0 + (l&15))*64 + k0 + (l>>4)*8];
    #pragma unroll
    for (int mt = 0; mt < 4; mt++) {
      f16x8 af = *(const f16x8*)&XT[(mt*16 + (l&15))*72 + k0 + (l>>4)*8];
      acc[mt] = MFMA16(af, bf, acc[mt]);
    }
  }
  const int d = n0 + (l&15);
  const float be = benc[d];
  float s = 0.0f, ss = 0.0f;
  #pragma unroll
  for (int mt = 0; mt < 4; mt++)
    #pragma unroll
    for (int j = 0; j < 4; j++) {
      const int t = mt*16 + (l>>4)*4 + j;
      const float v = acc[mt][j] + be;
      YS[t*136 + d] = __float2half(v);
      s += v; ss += v*v;
    }
  s  += __shfl_xor(s, 16);  s  += __shfl_xor(s, 32);
  ss += __shfl_xor(ss, 16); ss += __shfl_xor(ss, 32);
  if (l < 16) {
    atomicAdd(ws + WOFF_STATS + d, s);
    atomicAdd(ws + WOFF_STATS + DE + d, ss);
  }
  __syncthreads();
  __half* y = (__half*)(ws + WOFF_Y);
  const int row = tid >> 3, d0 = (tid & 7)*16;
  *(f16x8*)&y[(row0+row)*DE + d0]     = *(const f16x8*)&YS[row*136 + d0];
  *(f16x8*)&y[(row0+row)*DE + d0 + 8] = *(const f16x8*)&YS[row*136 + d0 + 8];
}

// ============================ k_A: BN + B-proj -> Bu(global) + LDS scan -> SL ============================
__global__ __launch_bounds__(512, 4) void k_A(
    const __half* __restrict__ hin, float* __restrict__ ws,
    const float* __restrict__ bnsg, const float* __restrict__ bnbg, int iblk)
{
  __shared__ __half U[32*136];
  __shared__ __half BU[32*536];
  __shared__ float AC[256];
  const int tid = threadIdx.x, w = tid >> 6, l = tid & 63, q = l >> 4, r = l & 15;
  const int b = blockIdx.y, cbg = blockIdx.x;
  const int h = tid & 255;
  if (tid < 128) {
    const float inv = 1.0f / (float)NROWS;
    const float s  = ws[WOFF_STATS + ((size_t)iblk*2+0)*DE + tid];
    const float sq = ws[WOFF_STATS + ((size_t)iblk*2+1)*DE + tid];
    const float mean = s*inv;
    const float var  = sq*inv - mean*mean;
    const float a = rsqrtf(var + EPSF) * bnsg[iblk*DE + tid];
    AC[tid]       = a;
    AC[128 + tid] = bnbg[iblk*DE + tid] - mean*a;
  }
  const __half* BG = (const __half*)(ws + WOFF_W16) + HOFF_BG + (size_t)iblk*512*128;
  const int n0 = w*64;
  const float lr = ws[WOFF_LAM + ((size_t)iblk*HH+h)*2+0];
  const float li = ws[WOFF_LAM + ((size_t)iblk*HH+h)*2+1];
  f16x8 bg4[4][4];
  #pragma unroll
  for (int nt = 0; nt < 4; nt++)
    #pragma unroll
    for (int k = 0; k < 4; k++)
      bg4[nt][k] = *(const f16x8*)&BG[(size_t)(n0 + nt*16 + r)*128 + k*32 + q*8];
  __half* bug = (__half*)(ws + WOFF_BU);
  __syncthreads();

  for (int it = 0; it < 4; it++) {
    const int cb = cbg*4 + it;
    const int row0 = b*TT + cb*32;
    {
      const int row = tid >> 4, d0 = (tid & 15)*8;
      f16x8 hv = *(const f16x8*)(hin + (size_t)(row0+row)*DE + d0);
      f16x8 uv;
      #pragma unroll
      for (int j = 0; j < 8; j++)
        uv[j] = (_Float16)((float)hv[j]*AC[d0+j] + AC[128+d0+j]);
      *(f16x8*)&U[row*136 + d0] = uv;
    }
    __syncthreads();
    {
      f32x4 acc[2][4];
      #pragma unroll
      for (int mt = 0; mt < 2; mt++)
        #pragma unroll
        for (int nt = 0; nt < 4; nt++) acc[mt][nt] = (f32x4)(0.0f);
      #pragma unroll
      for (int k = 0; k < 4; k++) {
        f16x8 af0 = *(const f16x8*)&U[(r)*136      + k*32 + q*8];
        f16x8 af1 = *(const f16x8*)&U[(16 + r)*136 + k*32 + q*8];
        #pragma unroll
        for (int nt = 0; nt < 4; nt++) {
          acc[0][nt] = MFMA16(af0, bg4[nt][k], acc[0][nt]);
          acc[1][nt] = MFMA16(af1, bg4[nt][k], acc[1][nt]);
        }
      }
      #pragma unroll
      for (int mt = 0; mt < 2; mt++)
        #pragma unroll
        for (int nt = 0; nt < 4; nt++) {
          f16x4 pk;
          #pragma unroll
          for (int j = 0; j < 4; j++) {
            pk[j] = (_Float16)acc[mt][nt][j];
            BU[(mt*16 + q*4 + j)*536 + n0 + nt*16 + r] = __float2half(acc[mt][nt][j]);
          }
          const int hc = n0 + nt*16 + r;
          *(f16x4*)(bug + (((size_t)(b*NC32 + cb)*512 + hc)*32 + mt*16 + q*4)) = pk;
        }
    }
    __syncthreads();
    if (tid < 256) {
      float sr = 0.0f, si = 0.0f;
      #pragma unroll
      for (int t = 0; t < 32; t++) {
        const float br = (float)BU[t*536 + h];
        const float bi = (float)BU[t*536 + 256 + h];
        const float nr = lr*sr - li*si + br;
        const float ni = lr*si + li*sr + bi;
        sr = nr; si = ni;
      }
      *((float2*)(ws + WOFF_SL) + ((size_t)b*NC32 + cb)*HH + h) = float2{sr, si};
    }
    __syncthreads();
  }
}

// ============================ k_carry ============================
__global__ void k_carry(float* __restrict__ ws, int i)
{
  const int b = blockIdx.x >> 2;
  const int h = (blockIdx.x & 3)*64 + threadIdx.x;
  const float Lr = ws[WOFF_LAML + ((size_t)i*HH+h)*2+0];
  const float Li = ws[WOFF_LAML + ((size_t)i*HH+h)*2+1];
  float2* C = (float2*)(ws + WOFF_CARRY) + (size_t)b*NC32*HH + h;
  const float2* S = (const float2*)(ws + WOFF_SL) + (size_t)b*NC32*HH + h;
  float sr = 0.0f, si = 0.0f;
  C[0] = float2{0.0f, 0.0f};
  for (int c0 = 0; c0 < 120; c0 += 8) {
    float2 sl[8];
    #pragma unroll
    for (int j = 0; j < 8; j++) sl[j] = S[(size_t)(c0+j)*HH];
    #pragma unroll
    for (int j = 0; j < 8; j++) {
      const float nr = Lr*sr - Li*si + sl[j].x;
      const float ni = Lr*si + Li*sr + sl[j].y;
      sr = nr; si = ni;
      C[(size_t)(c0+j+1)*HH] = float2{sr, si};
    }
  }
  {
    float2 sl[7];
    #pragma unroll
    for (int j = 0; j < 7; j++) sl[j] = S[(size_t)(120+j)*HH];
    #pragma unroll
    for (int j = 0; j < 7; j++) {
      const float nr = Lr*sr - Li*si + sl[j].x;
      const float ni = Lr*si + Li*sr + sl[j].y;
      sr = nr; si = ni;
      C[(size_t)(121+j)*HH] = float2{sr, si};
    }
  }
}

// ============================ k_BC: M=64 tiles, re/im-split C-proj, no cross-barrier arrays ============================
__global__ __launch_bounds__(512, 2) void k_BC(
    const __half* __restrict__ hin, float* __restrict__ ws,
    const float* __restrict__ bnsg, const float* __restrict__ bnbg,
    const float* __restrict__ b1g, const float* __restrict__ b2g,
    const float* __restrict__ Dvg, int iblk, int islast)
{
  __shared__ __half U[64*SU];      // BN'd u -> (P3) residual y -> (P4) h' staging
  __shared__ __half HT[64*SH];     // scan re -> scan im -> G
  __shared__ __half YL[64*SU];
  __shared__ float AC[256];
  __shared__ float DVs[128];
  const int tid = threadIdx.x, w = tid >> 6, l = tid & 63, q = l >> 4, r = l & 15;
  const int b = blockIdx.y, cbg = blockIdx.x;    // 32 groups × 4 chunks (2 tiles of 64 rows)
  const __half* w16 = (const __half*)(ws + WOFF_W16);
  const int d = w*16 + r;
  const int h = tid & 255, cl = tid >> 8;        // scan job: chunk-local cl, channel h

  if (tid < 128) {
    const float inv = 1.0f / (float)NROWS;
    const float s  = ws[WOFF_STATS + ((size_t)iblk*2+0)*DE + tid];
    const float sq = ws[WOFF_STATS + ((size_t)iblk*2+1)*DE + tid];
    const float mean = s*inv;
    const float var  = sq*inv - mean*mean;
    const float a = rsqrtf(var + EPSF) * bnsg[iblk*DE + tid];
    AC[tid]       = a;
    AC[128 + tid] = bnbg[iblk*DE + tid] - mean*a;
    DVs[tid] = Dvg[iblk*DE + tid];
  }

  const float lr = ws[WOFF_LAM + ((size_t)iblk*HH+h)*2+0];
  const float li = ws[WOFF_LAM + ((size_t)iblk*HH+h)*2+1];
  float b1a[2], b1b[2];
  #pragma unroll
  for (int nt = 0; nt < 2; nt++) {
    const int ca = w*32 + nt*16 + r;
    b1a[nt] = b1g[(size_t)iblk*LDIM + ca];
    b1b[nt] = b1g[(size_t)iblk*LDIM + 256 + ca];
  }
  const float bb2 = b2g[(size_t)iblk*DE + d];
  const __half* WC  = w16 + HOFF_WC + (size_t)iblk*128*512;
  const __half* W1T = w16 + HOFF_W1 + (size_t)iblk*512*128;
  const __half* W2T = w16 + HOFF_W2 + (size_t)iblk*128*256;
  const __half* bug = (const __half*)(ws + WOFF_BU);
  const __half* yh = (const __half*)(ws + WOFF_Y);
  __half* hh = (__half*)(ws + WOFF_H);
  float s_acc = 0.0f, ss_acc = 0.0f;
  __syncthreads();

  for (int it = 0; it < 2; it++) {               // 2 tiles × 64 rows
    const int cb0 = cbg*4 + it*2;                // first chunk of tile
    const int row0 = b*TT + cb0*32;

    // ---- P1: coalesced hin load; BN -> U; scan (si in regs) -> HT ----
    {
      const int row = tid >> 3, d0 = (tid & 7)*16;
      const __half* hp = hin + (size_t)(row0+row)*DE + d0;
      f16x8 h0 = *(const f16x8*)hp, h1 = *(const f16x8*)(hp+8);
      f16x8 u0, u1;
      #pragma unroll
      for (int j = 0; j < 8; j++) {
        u0[j] = (_Float16)((float)h0[j]*AC[d0+j]   + AC[128+d0+j]);
        u1[j] = (_Float16)((float)h1[j]*AC[d0+8+j] + AC[128+d0+8+j]);
      }
      *(f16x8*)&U[row*SU + d0]     = u0;
      *(f16x8*)&U[row*SU + d0 + 8] = u1;
    }
    f16x8 si8[4];
    {
      const int cb = cb0 + cl;
      const __half* bu = bug + ((size_t)(b*NC32 + cb)*512)*32;
      f16x8 bre[4], bim[4];
      #pragma unroll
      for (int k = 0; k < 4; k++) {
        bre[k] = *(const f16x8*)(bu + (size_t)h*32 + k*8);
        bim[k] = *(const f16x8*)(bu + (size_t)(256+h)*32 + k*8);
      }
      const float2 carry = *((const float2*)(ws + WOFF_CARRY) + ((size_t)b*NC32 + cb)*HH + h);
      float sr = carry.x, si = carry.y;
      #pragma unroll
      for (int t = 0; t < 32; t++) {
        const float br = (float)bre[t>>3][t&7];
        const float bi = (float)bim[t>>3][t&7];
        const float nr = lr*sr - li*si + br;
        const float ni = lr*si + li*sr + bi;
        sr = nr; si = ni;
        HT[(cl*32 + t)*SH + h] = __float2half(sr);
        si8[t>>3][t&7] = (_Float16)si;
      }
    }
    __syncthreads();

    // ---- P2a: C-proj re-half (K=256) ----
    f32x4 acc[4];
    #pragma unroll
    for (int mt = 0; mt < 4; mt++) acc[mt] = (f32x4)(0.0f);
    {
      f16x8 wcre[8];
      #pragma unroll
      for (int k = 0; k < 8; k++)
        wcre[k] = *(const f16x8*)&WC[(size_t)d*512 + k*32 + q*8];
      #pragma unroll
      for (int k = 0; k < 8; k++)
        #pragma unroll
        for (int mt = 0; mt < 4; mt++) {
          f16x8 af = *(const f16x8*)&HT[(mt*16 + r)*SH + k*32 + q*8];
          acc[mt] = MFMA16(af, wcre[k], acc[mt]);
        }
    }
    __syncthreads();
    // ---- swap si into HT ----
    #pragma unroll
    for (int t = 0; t < 32; t++)
      HT[(cl*32 + t)*SH + h] = si8[t>>3][t&7];
    __syncthreads();
    // ---- P2b: C-proj im-half (K=256) + u*D -> YL ----
    {
      f16x8 wcim[8];
      #pragma unroll
      for (int k = 0; k < 8; k++)
        wcim[k] = *(const f16x8*)&WC[(size_t)d*512 + 256 + k*32 + q*8];
      #pragma unroll
      for (int k = 0; k < 8; k++)
        #pragma unroll
        for (int mt = 0; mt < 4; mt++) {
          f16x8 af = *(const f16x8*)&HT[(mt*16 + r)*SH + k*32 + q*8];
          acc[mt] = MFMA16(af, wcim[k], acc[mt]);
        }
      const float dv = DVs[d];
      #pragma unroll
      for (int mt = 0; mt < 4; mt++)
        #pragma unroll
        for (int j = 0; j < 4; j++) {
          const int t = mt*16 + q*4 + j;
          const float u = (float)U[t*SU + d];
          YL[t*SU + d] = __float2half(acc[mt][j] + u*dv);
        }
    }
    __syncthreads();

    // ---- P3: load y -> U (coalesced, u dead); W1 + GLU -> HT ----
    {
      const int row = tid >> 3, d0 = (tid & 7)*16;
      const __half* yp = yh + (size_t)(row0+row)*DE + d0;
      *(f16x8*)&U[row*SU + d0]     = *(const f16x8*)yp;
      *(f16x8*)&U[row*SU + d0 + 8] = *(const f16x8*)(yp+8);
    }
    {
      #pragma unroll
      for (int nt = 0; nt < 2; nt++) {
        const int ca = w*32 + nt*16 + r;
        f16x8 wa[4], wb[4];
        #pragma unroll
        for (int k = 0; k < 4; k++) {
          wa[k] = *(const f16x8*)&W1T[(size_t)ca*128 + k*32 + q*8];
          wb[k] = *(const f16x8*)&W1T[(size_t)(256+ca)*128 + k*32 + q*8];
        }
        f32x4 aa[4], ab[4];
        #pragma unroll
        for (int mt = 0; mt < 4; mt++) { aa[mt] = (f32x4)(0.0f); ab[mt] = (f32x4)(0.0f); }
        #pragma unroll
        for (int k = 0; k < 4; k++)
          #pragma unroll
          for (int mt = 0; mt < 4; mt++) {
            f16x8 af = *(const f16x8*)&YL[(mt*16 + r)*SU + k*32 + q*8];
            aa[mt] = MFMA16(af, wa[k], aa[mt]);
            ab[mt] = MFMA16(af, wb[k], ab[mt]);
          }
        #pragma unroll
        for (int mt = 0; mt < 4; mt++)
          #pragma unroll
          for (int j = 0; j < 4; j++) {
            const int t = mt*16 + q*4 + j;
            const float av = aa[mt][j] + b1a[nt];
            const float bv = ab[mt][j] + b1b[nt];
            HT[t*SH + ca] = __float2half(av / (1.0f + __expf(-bv)));
          }
      }
    }
    __syncthreads();

    // ---- P4: h' = G @ W2 + b2 + y(U) -> U, stats ----
    {
      f16x8 w2f[8];
      #pragma unroll
      for (int k = 0; k < 8; k++)
        w2f[k] = *(const f16x8*)&W2T[(size_t)d*256 + k*32 + q*8];
      f32x4 a2[4];
      #pragma unroll
      for (int mt = 0; mt < 4; mt++) a2[mt] = (f32x4)(0.0f);
      #pragma unroll
      for (int k = 0; k < 8; k++)
        #pragma unroll
        for (int mt = 0; mt < 4; mt++) {
          f16x8 af = *(const f16x8*)&HT[(mt*16 + r)*SH + k*32 + q*8];
          a2[mt] = MFMA16(af, w2f[k], a2[mt]);
        }
      #pragma unroll
      for (int mt = 0; mt < 4; mt++)
        #pragma unroll
        for (int j = 0; j < 4; j++) {
          const int t = mt*16 + q*4 + j;
          const float v = a2[mt][j] + bb2 + (float)U[t*SU + d];
          U[t*SU + d] = __float2half(v);
          s_acc += v; ss_acc += v*v;
        }
    }
    __syncthreads();

    // ---- P5: coalesced writeback ----
    {
      const int row = tid >> 3, d0 = (tid & 7)*16;
      *(f16x8*)(hh + (size_t)(row0+row)*DE + d0)     = *(const f16x8*)&U[row*SU + d0];
      *(f16x8*)(hh + (size_t)(row0+row)*DE + d0 + 8) = *(const f16x8*)&U[row*SU + d0 + 8];
    }
    __syncthreads();
  }

  s_acc  += __shfl_xor(s_acc, 16);  s_acc  += __shfl_xor(s_acc, 32);
  ss_acc += __shfl_xor(ss_acc, 16); ss_acc += __shfl_xor(ss_acc, 32);
  if (l < 16) {
    atomicAdd(ws + WOFF_STATS + (size_t)((iblk+1)*2 + 0)*DE + d, s_acc);
    atomicAdd(ws + WOFF_STATS + (size_t)((iblk+1)*2 + 1)*DE + d, ss_acc);
    if (islast) atomicAdd(ws + WOFF_POOL + (size_t)b*DE + d, s_acc);
  }
}

// ============================ final projection ============================
__global__ void k_out(const float* __restrict__ Wout, const float* __restrict__ bout,
                      const float* __restrict__ ws, float* __restrict__ out)
{
  const int tid = threadIdx.x;
  if (tid < BB*ODIM) {
    const int b = tid / ODIM, o = tid % ODIM;
    float acc = bout[o];
    const float* p = ws + WOFF_POOL + (size_t)b*DE;
    const float invT = 1.0f / (float)TT;
    for (int d = 0; d < DE; d++) acc += p[d]*invT*Wout[d*ODIM + o];
    out[tid] = acc;
  }
}

extern "C" void kernel_launch(void* const* d_in, const int* in_sizes, int n_in,
                              void* d_out, int out_size, void* d_ws, size_t ws_size,
                              hipStream_t stream)
{
  const float* x   = (const float*)d_in[0];
  const float* nu  = (const float*)d_in[1];
  const float* th  = (const float*)d_in[2];
  const float* Bre = (const float*)d_in[3];
  const float* Bim = (const float*)d_in[4];
  const float* Cre = (const float*)d_in[5];
  const float* Cim = (const float*)d_in[6];
  const float* Dv  = (const float*)d_in[7];
  const float* W1  = (const float*)d_in[8];
  const float* b1  = (const float*)d_in[9];
  const float* W2  = (const float*)d_in[10];
  const float* b2  = (const float*)d_in[11];
  const float* bns = (const float*)d_in[12];
  const float* bnb = (const float*)d_in[13];
  const float* We  = (const float*)d_in[14];
  const float* be  = (const float*)d_in[15];
  const float* Wo  = (const float*)d_in[16];
  const float* bo  = (const float*)d_in[17];
  float* ws = (float*)d_ws;
  float* out = (float*)d_out;

  hipMemsetAsync(ws + WOFF_STATS, 0,
                 (size_t)(((NBLKS+1)*2*DE) + BB*DE)*sizeof(float), stream);

  k_prep<<<dim3(NBLKS, 16), 256, 0, stream>>>(nu, th, Bre, Bim, Cre, Cim, W1, W2, We, ws);
  k_enc<<<NROWS/64, 512, 0, stream>>>(x, be, ws);

  const __half* Yh = (const __half*)(ws + WOFF_Y);
  const __half* Hh = (const __half*)(ws + WOFF_H);
  for (int i = 0; i < NBLKS; i++) {
    const __half* hin = (i == 0) ? Yh : Hh;
    k_A    <<<dim3(32, BB), 512, 0, stream>>>(hin, ws, bns, bnb, i);
    k_carry<<<64, 64, 0, stream>>>(ws, i);
    k_BC   <<<dim3(32, BB), 512, 0, stream>>>(hin, ws, bns, bnb, b1, b2, Dv, i,
                                              (i == NBLKS-1) ? 1 : 0);
  }
  k_out<<<1, 256, 0, stream>>>(Wo, bo, ws, out);
}